// Round 13
// baseline (241.425 us; speedup 1.0000x reference)
//
#include <hip/hip_runtime.h>

#define B_ 512
#define T_ 512
#define I_ 64
#define H_ 128

// LDS: 4 f32 h buffers (512B each) + dummy dump region
#define HA0    0
#define HA1    512
#define HBB0   1024
#define HBB1   1536
#define DUMMY  2048
#define LDS_SZ 2304

#define FM(a, x, w) "v_fmac_f32 v" #a ", v" #x ", v" #w "\n\t"
#define SC(n) "v_mul_f32 v" #n ", 0x4038aa3b, v" #n "\n\t"   // *= 2*log2(e)

#define CLOBS \
    "v32","v33","v34","v35","v36","v37","v38","v39","v40","v41","v42","v43", \
    "v44","v45","v46","v47","v48","v49","v50","v51","v52","v53","v54","v55", \
    "v56","v57","v58","v59","v60","v61","v62","v63","v64","v65","v66","v67", \
    "v68","v69","v70","v71","v72","v73","v74","v75","v76","v77","v78","v79", \
    "v80","v81","v82","v83","v84","v85","v86","v87","v88","v89","v90","v91", \
    "v92","v93","v94","v95","v96","v97","v98","v99","v100","v101","v102", \
    "v103","v104","v105","v106","v107","v108","v109","v110","v111","v112", \
    "v113","v114","v115","v116","v117","v118","v119","v120","v121","v122", \
    "v123","v124","v125","v126","v127","memory"

// Round-9-proven step (registers/layout/reduce identical). Deltas:
//  - vmcnt(3) -> vmcnt(7): two interleaved 4-deep tok prefetch streams (A,B).
//  - TAIL parameter: row A ends after ds_write (write drained by row B's
//    tail, which follows in program order); row B ends lgkm(0)+s_barrier.
// Tok sets: row A v56-71, row B v32-47. Scratch: acc v48-51, tmp v52-55,
// h v72-79. Weights (shared by both rows): wh v80-111, wi v112-127.
#define RNN_STEP(TA, TB, TC, TD, VOFF, HRD, HWR, SB, TAIL)                    \
    asm volatile(                                                             \
        "ds_read_b128 v[72:75], %1\n\t"                                       \
        "ds_read_b128 v[76:79], %1 offset:256\n\t"                            \
        "s_waitcnt vmcnt(7)\n\t"                                              \
        "v_fma_f32 v48, v" #TA ", v112, %3\n\t"                               \
        "v_fma_f32 v49, v" #TA ", v116, %4\n\t"                               \
        "v_fma_f32 v50, v" #TA ", v120, %5\n\t"                               \
        "v_fma_f32 v51, v" #TA ", v124, %6\n\t"                               \
        FM(48,TB,113) FM(49,TB,117) FM(50,TB,121) FM(51,TB,125)               \
        FM(48,TC,114) FM(49,TC,118) FM(50,TC,122) FM(51,TC,126)               \
        FM(48,TD,115) FM(49,TD,119) FM(50,TD,123) FM(51,TD,127)               \
        "global_load_dwordx4 v[" #TA ":" #TD "], %0, %9\n\t"                  \
        "v_add_u32 %0, 0x100, %0\n\t"                                         \
        "v_and_b32 %0, 0x1ffff, %0\n\t"                                       \
        "s_waitcnt lgkmcnt(1)\n\t"                                            \
        FM(48,72,80) FM(49,72,88) FM(50,72,96)  FM(51,72,104)                 \
        FM(48,73,81) FM(49,73,89) FM(50,73,97)  FM(51,73,105)                 \
        FM(48,74,82) FM(49,74,90) FM(50,74,98)  FM(51,74,106)                 \
        FM(48,75,83) FM(49,75,91) FM(50,75,99)  FM(51,75,107)                 \
        "s_waitcnt lgkmcnt(0)\n\t"                                            \
        FM(48,76,84) FM(49,76,92) FM(50,76,100) FM(51,76,108)                 \
        FM(48,77,85) FM(49,77,93) FM(50,77,101) FM(51,77,109)                 \
        FM(48,78,86) FM(49,78,94) FM(50,78,102) FM(51,78,110)                 \
        FM(48,79,87) FM(49,79,95) FM(50,79,103) FM(51,79,111)                 \
        "s_nop 1\n\t"                                                         \
        "v_add_f32 v48, v48, v48 quad_perm:[1,0,3,2] row_mask:0xf bank_mask:0xf\n\t" \
        "v_add_f32 v49, v49, v49 quad_perm:[1,0,3,2] row_mask:0xf bank_mask:0xf\n\t" \
        "v_add_f32 v50, v50, v50 quad_perm:[1,0,3,2] row_mask:0xf bank_mask:0xf\n\t" \
        "v_add_f32 v51, v51, v51 quad_perm:[1,0,3,2] row_mask:0xf bank_mask:0xf\n\t" \
        "v_cndmask_b32 v52, v48, v49, %7\n\t"                                 \
        "v_cndmask_b32 v53, v50, v51, %7\n\t"                                 \
        "s_nop 0\n\t"                                                         \
        "v_add_f32 v52, v52, v52 quad_perm:[2,3,0,1] row_mask:0xf bank_mask:0xf\n\t" \
        "v_add_f32 v53, v53, v53 quad_perm:[2,3,0,1] row_mask:0xf bank_mask:0xf\n\t" \
        "v_cndmask_b32 v54, v52, v53, %8\n\t"                                 \
        "s_nop 1\n\t"                                                         \
        "v_add_f32 v54, v54, v54 row_shl:8 row_mask:0xf bank_mask:0x3\n\t"    \
        "s_nop 1\n\t"                                                         \
        "v_add_f32 v54, v54, v54 row_shl:4 row_mask:0xf bank_mask:0x1\n\t"    \
        "s_nop 1\n\t"                                                         \
        "v_exp_f32 v54, v54\n\t"                                              \
        "s_nop 0\n\t"                                                         \
        "v_add_f32 v54, 1.0, v54\n\t"                                         \
        "v_rcp_f32 v55, v54\n\t"                                              \
        "s_nop 0\n\t"                                                         \
        "v_fma_f32 v54, v55, -2.0, 1.0\n\t"                                   \
        "ds_write_b32 %2, v54\n\t"                                            \
        TAIL                                                                  \
        : "+v"(VOFF)                                                          \
        : "v"(HRD), "v"(HWR), "v"(biasA), "v"(biasB), "v"(biasC),             \
          "v"(biasD), "s"(M1), "s"(M2), "s"(SB)                               \
        : CLOBS)

#define TAIL_A ""
#define TAIL_B "s_waitcnt lgkmcnt(0)\n\ts_barrier"

__global__ __launch_bounds__(512) __attribute__((amdgpu_waves_per_eu(4, 4)))
void rnn_kernel(const float* __restrict__ token,
                const float* __restrict__ W_ih,
                const float* __restrict__ W_hh,
                const float* __restrict__ b_ih,
                const float* __restrict__ b_hh,
                const float* __restrict__ W_lin,
                const float* __restrict__ b_lin,
                float* __restrict__ out)
{
    __shared__ __align__(16) char lds[LDS_SZ];
    const unsigned lb =
        (unsigned)(uintptr_t)(__attribute__((address_space(3))) char*)lds;

    const int tid = threadIdx.x;
    const int e   = tid & 15;         // K-sixteenth
    const int G   = tid >> 4;         // output-quad id 0..31
    const int b   = blockIdx.x;       // rows 2b (A) and 2b+1 (B)
    const int jb  = 4 * G;

    // ---- weights (shared by both rows) into v80-127, round-9-verbatim ----
    {
        const float* pWh = W_hh + jb * H_ + e * 8;
        const float* pWi = W_ih + jb * I_ + e * 4;
        asm volatile(
            "global_load_dwordx4 v[80:83],   %0, off\n\t"
            "global_load_dwordx4 v[84:87],   %0, off offset:16\n\t"
            "global_load_dwordx4 v[88:91],   %0, off offset:512\n\t"
            "global_load_dwordx4 v[92:95],   %0, off offset:528\n\t"
            "global_load_dwordx4 v[96:99],   %0, off offset:1024\n\t"
            "global_load_dwordx4 v[100:103], %0, off offset:1040\n\t"
            "global_load_dwordx4 v[104:107], %0, off offset:1536\n\t"
            "global_load_dwordx4 v[108:111], %0, off offset:1552\n\t"
            "global_load_dwordx4 v[112:115], %1, off\n\t"
            "global_load_dwordx4 v[116:119], %1, off offset:256\n\t"
            "global_load_dwordx4 v[120:123], %1, off offset:512\n\t"
            "global_load_dwordx4 v[124:127], %1, off offset:768\n\t"
            "s_waitcnt vmcnt(0)\n\t"
            SC(80) SC(81) SC(82) SC(83) SC(84) SC(85) SC(86) SC(87)
            SC(88) SC(89) SC(90) SC(91) SC(92) SC(93) SC(94) SC(95)
            SC(96) SC(97) SC(98) SC(99) SC(100) SC(101) SC(102) SC(103)
            SC(104) SC(105) SC(106) SC(107) SC(108) SC(109) SC(110) SC(111)
            SC(112) SC(113) SC(114) SC(115) SC(116) SC(117) SC(118) SC(119)
            SC(120) SC(121) SC(122) SC(123) SC(124) SC(125) SC(126) SC(127)
            :: "v"(pWh), "v"(pWi) : CLOBS);
    }

    const float k16 = 2.885390081777927f / 16.0f;
    const float biasA = (b_ih[jb + 0] + b_hh[jb + 0]) * k16;
    const float biasB = (b_ih[jb + 1] + b_hh[jb + 1]) * k16;
    const float biasC = (b_ih[jb + 2] + b_hh[jb + 2]) * k16;
    const float biasD = (b_ih[jb + 3] + b_hh[jb + 3]) * k16;
    const unsigned long long M1 = 0xAAAAAAAAAAAAAAAAULL;
    const unsigned long long M2 = 0xCCCCCCCCCCCCCCCCULL;

    // round-9-proven permuted h layout
    const int  jsel   = jb + (e & 3);
    const int  wbyte  = ((((jsel >> 2) & 1) * 16 + (jsel >> 3)) * 16) + (jsel & 3) * 4;
    const bool writer = (e < 4);
    const unsigned dmy  = lb + DUMMY + (tid & 63) * 4;
    const unsigned hwA0 = writer ? (lb + HA1 + wbyte) : dmy;   // A buf0->buf1
    const unsigned hwA1 = writer ? (lb + HA0 + wbyte) : dmy;
    const unsigned hwB0 = writer ? (lb + HBB1 + wbyte) : dmy;  // B buf0->buf1
    const unsigned hwB1 = writer ? (lb + HBB0 + wbyte) : dmy;
    const unsigned hrA0 = lb + HA0 + e * 16;
    const unsigned hrA1 = lb + HA1 + e * 16;
    const unsigned hrB0 = lb + HBB0 + e * 16;
    const unsigned hrB1 = lb + HBB1 + e * 16;

    const unsigned long long sbA =
        (unsigned long long)(uintptr_t)(token + (size_t)(2 * b) * T_ * I_);
    const unsigned long long sbB =
        (unsigned long long)(uintptr_t)(token + (size_t)(2 * b + 1) * T_ * I_);

    // ---- prologue: issue tok(0..3) for both rows, strict A,B interleave ----
    {
        const unsigned v0 = e * 16;
        asm volatile(
            "global_load_dwordx4 v[56:59], %0, %1\n\t"               // A0
            "global_load_dwordx4 v[32:35], %0, %2\n\t"               // B0
            "global_load_dwordx4 v[60:63], %0, %1 offset:256\n\t"    // A1
            "global_load_dwordx4 v[36:39], %0, %2 offset:256\n\t"    // B1
            "global_load_dwordx4 v[64:67], %0, %1 offset:512\n\t"    // A2
            "global_load_dwordx4 v[40:43], %0, %2 offset:512\n\t"    // B2
            "global_load_dwordx4 v[68:71], %0, %1 offset:768\n\t"    // A3
            "global_load_dwordx4 v[44:47], %0, %2 offset:768\n\t"    // B3
            :: "v"(v0), "s"(sbA), "s"(sbB) : CLOBS);
    }
    unsigned voffA = e * 16 + 1024;
    unsigned voffB = e * 16 + 1024;
    if (tid < H_) {
        *(float*)(lds + HA0  + tid * 4) = 0.0f;
        *(float*)(lds + HBB0 + tid * 4) = 0.0f;
    }
    asm volatile("s_waitcnt lgkmcnt(0)\n\ts_barrier" ::: "memory");

    // Pair structure: [A-step, B-step+barrier] x2 per 2 time steps.
    // A's write is drained by B's tail lgkm(0); one barrier per 2 row-steps.
#pragma unroll 1
    for (int t = 0; t < T_; t += 4) {
        RNN_STEP(56, 57, 58, 59, voffA, hrA0, hwA0, sbA, TAIL_A);  // A t+0
        RNN_STEP(32, 33, 34, 35, voffB, hrB0, hwB0, sbB, TAIL_B);  // B t+0
        RNN_STEP(60, 61, 62, 63, voffA, hrA1, hwA1, sbA, TAIL_A);  // A t+1
        RNN_STEP(36, 37, 38, 39, voffB, hrB1, hwB1, sbB, TAIL_B);  // B t+1
        RNN_STEP(64, 65, 66, 67, voffA, hrA0, hwA0, sbA, TAIL_A);  // A t+2
        RNN_STEP(40, 41, 42, 43, voffB, hrB0, hwB0, sbB, TAIL_B);  // B t+2
        RNN_STEP(68, 69, 70, 71, voffA, hrA1, hwA1, sbA, TAIL_A);  // A t+3
        RNN_STEP(44, 45, 46, 47, voffB, hrB1, hwB1, sbB, TAIL_B);  // B t+3
    }

    // drain dangling wrapped prefetches (in-row, harmless)
    asm volatile("s_waitcnt vmcnt(0)" ::: "memory");

    // ---- heads: wave 0 -> row A -> out[2b]; wave 1 -> row B -> out[2b+1] ----
    if (tid < 128) {
        const int row = tid >> 6;
        const int a0  = tid & 63, a1 = (tid & 63) + 64;
        const int l0  = (((a0 >> 2) & 1) * 16 + (a0 >> 3)) * 4 + (a0 & 3);
        const int l1  = (((a1 >> 2) & 1) * 16 + (a1 >> 3)) * 4 + (a1 & 3);
        const int hb  = row ? HBB0 : HA0;   // 512 even steps -> final h in buf0
        float p = *(const float*)(lds + hb + l0 * 4) * W_lin[a0]
                + *(const float*)(lds + hb + l1 * 4) * W_lin[a1];
#pragma unroll
        for (int off = 32; off; off >>= 1) p += __shfl_down(p, off);
        if ((tid & 63) == 0) out[2 * b + row] = p + b_lin[0];
    }
}

extern "C" void kernel_launch(void* const* d_in, const int* in_sizes, int n_in,
                              void* d_out, int out_size, void* d_ws, size_t ws_size,
                              hipStream_t stream) {
    const float* token = (const float*)d_in[0];
    const float* W_ih  = (const float*)d_in[1];
    const float* W_hh  = (const float*)d_in[2];
    const float* b_ih  = (const float*)d_in[3];
    const float* b_hh  = (const float*)d_in[4];
    const float* W_lin = (const float*)d_in[5];
    const float* b_lin = (const float*)d_in[6];
    float* out = (float*)d_out;

    hipLaunchKernelGGL(rnn_kernel, dim3(B_ / 2), dim3(512), 0, stream,
                       token, W_ih, W_hh, b_ih, b_hh, W_lin, b_lin, out);
}

// Round 14
// 225.475 us; speedup vs baseline: 1.0707x; 1.0707x over previous
//
#include <hip/hip_runtime.h>

#define B_ 512
#define T_ 512
#define I_ 64
#define H_ 128

// LDS: h ping/pong bf16 (256B each) + dummy dump
#define HB0    0
#define HB1    256
#define DUMMY  512
#define LDS_SZ 768

#define FM(a,x,w)  "v_fmac_f32 v" #a ", v" #x ", v" #w "\n\t"
#define DT(A,X,W)  "v_dot2_f32_bf16 v" #A ", v" #X ", v" #W ", v" #A "\n\t"
#define PK(D,LO,HI) "v_cvt_pk_bf16_f32 v" #D ", v" #LO ", v" #HI "\n\t"
#define SC(n)      "v_mul_f32 v" #n ", 0x4038aa3b, v" #n "\n\t"   // *= 2*log2(e)
#define LDW(A,B,OFF) "global_load_dwordx4 v[" #A ":" #B "], %0, off offset:" #OFF "\n\t"

#define CLOBS \
    "v20","v21","v22","v23","v24","v25","v26","v27","v28","v29","v30","v31", \
    "v32","v33","v34","v35","v36","v37","v38","v39","v40","v41","v42","v43", \
    "v44","v45","v46","v47","v48","v49","v50","v51","v52","v53","v54","v55", \
    "v56","v57","v58","v59","v60","v61","v62","v63","v64","v65","v66","v67", \
    "v68","v69","v70","v71","v72","v73","v74","v75","v76","v77","v78","v79", \
    "v80","v81","v82","v83","v84","v85","v86","v87","v88","v89","v90","v91", \
    "v92","v93","v94","v95","v96","v97","v98","v99","v100","v101","v102", \
    "v103","v104","v105","v106","v107","v108","v109","v110","v111","v112", \
    "v113","v114","v115","v116","v117","v118","v119","memory"

// Register map (fixed):
//   accs a0-7: v20-27 (outputs jb..jb+7) ; c0-3: v28-31 ; d0,d1: v32,v33
//   tanh: v34,v35 ; h pairs: v36-39 ; tok T0-T3: v40-43/44-47/48-51/52-55
//   wi f32 (row r): v56+4r..+3 ; wh bf16 pairs (row r): v88+4r..+3
// Step: ds_read h (1 b128) hidden by 32 f32 proj FMA; 32 dot2 rec (round-10
// numerics); 16-lane reduce via round-9-proven DPP patterns; 2 ds_write_b16.
#define RNN_STEP(TA, TB, TC, TD, HRD, HWA, HWB)                               \
    asm volatile(                                                             \
        "ds_read_b128 v[36:39], %1\n\t"                                       \
        "s_waitcnt vmcnt(3)\n\t"                                              \
        "v_fma_f32 v20, v" #TA ", v56, %4\n\t"                                \
        "v_fma_f32 v21, v" #TA ", v60, %5\n\t"                                \
        "v_fma_f32 v22, v" #TA ", v64, %6\n\t"                                \
        "v_fma_f32 v23, v" #TA ", v68, %7\n\t"                                \
        "v_fma_f32 v24, v" #TA ", v72, %8\n\t"                                \
        "v_fma_f32 v25, v" #TA ", v76, %9\n\t"                                \
        "v_fma_f32 v26, v" #TA ", v80, %10\n\t"                               \
        "v_fma_f32 v27, v" #TA ", v84, %11\n\t"                               \
        FM(20,TB,57) FM(21,TB,61) FM(22,TB,65) FM(23,TB,69)                   \
        FM(24,TB,73) FM(25,TB,77) FM(26,TB,81) FM(27,TB,85)                   \
        FM(20,TC,58) FM(21,TC,62) FM(22,TC,66) FM(23,TC,70)                   \
        FM(24,TC,74) FM(25,TC,78) FM(26,TC,82) FM(27,TC,86)                   \
        FM(20,TD,59) FM(21,TD,63) FM(22,TD,67) FM(23,TD,71)                   \
        FM(24,TD,75) FM(25,TD,79) FM(26,TD,83) FM(27,TD,87)                   \
        "global_load_dwordx4 v[" #TA ":" #TD "], %0, %14\n\t"                 \
        "v_add_u32 %0, 0x100, %0\n\t"                                         \
        "v_and_b32 %0, 0x1ffff, %0\n\t"                                       \
        "s_waitcnt lgkmcnt(0)\n\t"                                            \
        DT(20,36,88)  DT(21,36,92)  DT(22,36,96)  DT(23,36,100)               \
        DT(24,36,104) DT(25,36,108) DT(26,36,112) DT(27,36,116)               \
        DT(20,37,89)  DT(21,37,93)  DT(22,37,97)  DT(23,37,101)               \
        DT(24,37,105) DT(25,37,109) DT(26,37,113) DT(27,37,117)               \
        DT(20,38,90)  DT(21,38,94)  DT(22,38,98)  DT(23,38,102)               \
        DT(24,38,106) DT(25,38,110) DT(26,38,114) DT(27,38,118)               \
        DT(20,39,91)  DT(21,39,95)  DT(22,39,99)  DT(23,39,103)               \
        DT(24,39,107) DT(25,39,111) DT(26,39,115) DT(27,39,119)               \
        /* xor1 on 8 accs (a0 written 8+ instrs ago: hazard-safe) */          \
        "v_add_f32 v20, v20, v20 quad_perm:[1,0,3,2] row_mask:0xf bank_mask:0xf\n\t" \
        "v_add_f32 v21, v21, v21 quad_perm:[1,0,3,2] row_mask:0xf bank_mask:0xf\n\t" \
        "v_add_f32 v22, v22, v22 quad_perm:[1,0,3,2] row_mask:0xf bank_mask:0xf\n\t" \
        "v_add_f32 v23, v23, v23 quad_perm:[1,0,3,2] row_mask:0xf bank_mask:0xf\n\t" \
        "v_add_f32 v24, v24, v24 quad_perm:[1,0,3,2] row_mask:0xf bank_mask:0xf\n\t" \
        "v_add_f32 v25, v25, v25 quad_perm:[1,0,3,2] row_mask:0xf bank_mask:0xf\n\t" \
        "v_add_f32 v26, v26, v26 quad_perm:[1,0,3,2] row_mask:0xf bank_mask:0xf\n\t" \
        "v_add_f32 v27, v27, v27 quad_perm:[1,0,3,2] row_mask:0xf bank_mask:0xf\n\t" \
        "v_cndmask_b32 v28, v20, v21, %12\n\t"                                \
        "v_cndmask_b32 v29, v22, v23, %12\n\t"                                \
        "v_cndmask_b32 v30, v24, v25, %12\n\t"                                \
        "v_cndmask_b32 v31, v26, v27, %12\n\t"                                \
        /* xor2 (v28 written 4 back: safe) */                                 \
        "v_add_f32 v28, v28, v28 quad_perm:[2,3,0,1] row_mask:0xf bank_mask:0xf\n\t" \
        "v_add_f32 v29, v29, v29 quad_perm:[2,3,0,1] row_mask:0xf bank_mask:0xf\n\t" \
        "v_add_f32 v30, v30, v30 quad_perm:[2,3,0,1] row_mask:0xf bank_mask:0xf\n\t" \
        "v_add_f32 v31, v31, v31 quad_perm:[2,3,0,1] row_mask:0xf bank_mask:0xf\n\t" \
        "v_cndmask_b32 v32, v28, v29, %13\n\t"                                \
        "v_cndmask_b32 v33, v30, v31, %13\n\t"                                \
        "s_nop 0\n\t"                                                         \
        /* xor8: lanes e<8 pull e+8 (same output: e&3 preserved) */           \
        "v_add_f32 v32, v32, v32 row_shl:8 row_mask:0xf bank_mask:0x3\n\t"    \
        "v_add_f32 v33, v33, v33 row_shl:8 row_mask:0xf bank_mask:0x3\n\t"    \
        "s_nop 0\n\t"                                                         \
        /* xor4: lanes e<4 pull e+4 -> full sums: v32=jb+e, v33=jb+4+e */     \
        "v_add_f32 v32, v32, v32 row_shl:4 row_mask:0xf bank_mask:0x1\n\t"    \
        "v_add_f32 v33, v33, v33 row_shl:4 row_mask:0xf bank_mask:0x1\n\t"    \
        "s_nop 1\n\t"                                                         \
        "v_exp_f32 v34, v32\n\t"                                              \
        "v_exp_f32 v35, v33\n\t"                                              \
        "s_nop 0\n\t"                                                         \
        "v_add_f32 v34, 1.0, v34\n\t"                                         \
        "v_add_f32 v35, 1.0, v35\n\t"                                         \
        "v_rcp_f32 v34, v34\n\t"                                              \
        "v_rcp_f32 v35, v35\n\t"                                              \
        "s_nop 0\n\t"                                                         \
        "v_fma_f32 v34, v34, -2.0, 1.0\n\t"                                   \
        "v_fma_f32 v35, v35, -2.0, 1.0\n\t"                                   \
        "v_cvt_pk_bf16_f32 v34, v34, v34\n\t"                                 \
        "v_cvt_pk_bf16_f32 v35, v35, v35\n\t"                                 \
        "ds_write_b16 %2, v34\n\t"                                            \
        "ds_write_b16 %3, v35\n\t"                                            \
        "s_waitcnt lgkmcnt(0)\n\t"                                            \
        "s_barrier"                                                           \
        : "+v"(voff)                                                          \
        : "v"(HRD), "v"(HWA), "v"(HWB),                                       \
          "v"(bias0), "v"(bias1), "v"(bias2), "v"(bias3),                     \
          "v"(bias4), "v"(bias5), "v"(bias6), "v"(bias7),                     \
          "s"(M1), "s"(M2), "s"(sbase)                                        \
        : CLOBS)

__global__ __launch_bounds__(256) __attribute__((amdgpu_waves_per_eu(2, 2)))
void rnn_kernel(const float* __restrict__ token,
                const float* __restrict__ W_ih,
                const float* __restrict__ W_hh,
                const float* __restrict__ b_ih,
                const float* __restrict__ b_hh,
                const float* __restrict__ W_lin,
                const float* __restrict__ b_lin,
                float* __restrict__ out)
{
    __shared__ __align__(16) char lds[LDS_SZ];
    const unsigned lb =
        (unsigned)(uintptr_t)(__attribute__((address_space(3))) char*)lds;

    const int tid = threadIdx.x;      // 256 threads = 4 waves
    const int e   = tid & 15;         // K-sixteenth
    const int G   = tid >> 4;         // output-octet id 0..15
    const int b   = blockIdx.x;       // one batch row per block
    const int jb  = 8 * G;

    // ---- wh: 8 rows x 8 f32 -> *K2 -> bf16 pairs v88-119 ----
    {
        const float* pWh = W_hh + jb * H_ + e * 8;   // row stride 512B
        asm volatile(
            LDW(56,59,0)    LDW(60,63,16)   LDW(64,67,512)  LDW(68,71,528)
            LDW(72,75,1024) LDW(76,79,1040) LDW(80,83,1536) LDW(84,87,1552)
            "s_waitcnt vmcnt(0)\n\t"
            SC(56) SC(57) SC(58) SC(59) SC(60) SC(61) SC(62) SC(63)
            SC(64) SC(65) SC(66) SC(67) SC(68) SC(69) SC(70) SC(71)
            SC(72) SC(73) SC(74) SC(75) SC(76) SC(77) SC(78) SC(79)
            SC(80) SC(81) SC(82) SC(83) SC(84) SC(85) SC(86) SC(87)
            PK(88,56,57)  PK(89,58,59)  PK(90,60,61)  PK(91,62,63)
            PK(92,64,65)  PK(93,66,67)  PK(94,68,69)  PK(95,70,71)
            PK(96,72,73)  PK(97,74,75)  PK(98,76,77)  PK(99,78,79)
            PK(100,80,81) PK(101,82,83) PK(102,84,85) PK(103,86,87)
            LDW(56,59,2048) LDW(60,63,2064) LDW(64,67,2560) LDW(68,71,2576)
            LDW(72,75,3072) LDW(76,79,3088) LDW(80,83,3584) LDW(84,87,3600)
            "s_waitcnt vmcnt(0)\n\t"
            SC(56) SC(57) SC(58) SC(59) SC(60) SC(61) SC(62) SC(63)
            SC(64) SC(65) SC(66) SC(67) SC(68) SC(69) SC(70) SC(71)
            SC(72) SC(73) SC(74) SC(75) SC(76) SC(77) SC(78) SC(79)
            SC(80) SC(81) SC(82) SC(83) SC(84) SC(85) SC(86) SC(87)
            PK(104,56,57) PK(105,58,59) PK(106,60,61) PK(107,62,63)
            PK(108,64,65) PK(109,66,67) PK(110,68,69) PK(111,70,71)
            PK(112,72,73) PK(113,74,75) PK(114,76,77) PK(115,78,79)
            PK(116,80,81) PK(117,82,83) PK(118,84,85) PK(119,86,87)
            :: "v"(pWh) : CLOBS);
    }
    // ---- wi: 8 rows x 4 f32 (kept f32, *K2) -> v56-87 ----
    {
        const float* pWi = W_ih + jb * I_ + e * 4;   // row stride 256B
        asm volatile(
            LDW(56,59,0)    LDW(60,63,256)  LDW(64,67,512)  LDW(68,71,768)
            LDW(72,75,1024) LDW(76,79,1280) LDW(80,83,1536) LDW(84,87,1792)
            "s_waitcnt vmcnt(0)\n\t"
            SC(56) SC(57) SC(58) SC(59) SC(60) SC(61) SC(62) SC(63)
            SC(64) SC(65) SC(66) SC(67) SC(68) SC(69) SC(70) SC(71)
            SC(72) SC(73) SC(74) SC(75) SC(76) SC(77) SC(78) SC(79)
            SC(80) SC(81) SC(82) SC(83) SC(84) SC(85) SC(86) SC(87)
            :: "v"(pWi) : CLOBS);
    }

    // biases K2/16-prescaled (16 lanes each contribute the seed)
    const float k16 = 2.885390081777927f / 16.0f;
    const float bias0 = (b_ih[jb+0] + b_hh[jb+0]) * k16;
    const float bias1 = (b_ih[jb+1] + b_hh[jb+1]) * k16;
    const float bias2 = (b_ih[jb+2] + b_hh[jb+2]) * k16;
    const float bias3 = (b_ih[jb+3] + b_hh[jb+3]) * k16;
    const float bias4 = (b_ih[jb+4] + b_hh[jb+4]) * k16;
    const float bias5 = (b_ih[jb+5] + b_hh[jb+5]) * k16;
    const float bias6 = (b_ih[jb+6] + b_hh[jb+6]) * k16;
    const float bias7 = (b_ih[jb+7] + b_hh[jb+7]) * k16;
    const unsigned long long M1 = 0xAAAAAAAAAAAAAAAAULL;  // lanes with e&1
    const unsigned long long M2 = 0xCCCCCCCCCCCCCCCCULL;  // lanes with e&2

    // h LINEAR bf16 (round-10 layout): h[j] at byte 2j; lane reads e*16..+15.
    const bool writer = (e < 4);
    const unsigned dmy = lb + DUMMY + (tid & 63) * 4;
    const unsigned hr0  = lb + HB0 + e * 16;
    const unsigned hr1  = lb + HB1 + e * 16;
    const unsigned hwa0 = writer ? (lb + HB1 + 2 * (jb + e))     : dmy;
    const unsigned hwb0 = writer ? (lb + HB1 + 2 * (jb + 4 + e)) : dmy;
    const unsigned hwa1 = writer ? (lb + HB0 + 2 * (jb + e))     : dmy;
    const unsigned hwb1 = writer ? (lb + HB0 + 2 * (jb + 4 + e)) : dmy;

    const unsigned long long sbase =
        (unsigned long long)(uintptr_t)(token + (size_t)b * T_ * I_);

    // ---- prologue: issue tok(0..3) into T0..T3; zero h buf0 ----
    {
        const unsigned v0 = e * 16;
        asm volatile(
            "global_load_dwordx4 v[40:43], %0, %1\n\t"
            "global_load_dwordx4 v[44:47], %0, %1 offset:256\n\t"
            "global_load_dwordx4 v[48:51], %0, %1 offset:512\n\t"
            "global_load_dwordx4 v[52:55], %0, %1 offset:768\n\t"
            :: "v"(v0), "s"(sbase) : CLOBS);
    }
    unsigned voff = e * 16 + 1024;    // next issue: tok(4)
    if (tid < H_) *(unsigned short*)(lds + HB0 + tid * 2) = 0;
    asm volatile("s_waitcnt lgkmcnt(0)\n\ts_barrier" ::: "memory");

#pragma unroll 1
    for (int t = 0; t < T_; t += 4) {
        RNN_STEP(40, 41, 42, 43, hr0, hwa0, hwb0);   // t+0: buf0 -> buf1
        RNN_STEP(44, 45, 46, 47, hr1, hwa1, hwb1);   // t+1: buf1 -> buf0
        RNN_STEP(48, 49, 50, 51, hr0, hwa0, hwb0);   // t+2
        RNN_STEP(52, 53, 54, 55, hr1, hwa1, hwb1);   // t+3
    }

    asm volatile("s_waitcnt vmcnt(0)" ::: "memory");  // dangling prefetches

    // ---- linear head on h buf0 (512 even steps -> final h in buf0) ----
    if (tid < 64) {
        unsigned u0 = *(const unsigned short*)(lds + HB0 + 2 * tid);
        unsigned u1 = *(const unsigned short*)(lds + HB0 + 2 * (tid + 64));
        float h0 = __uint_as_float(u0 << 16);
        float h1 = __uint_as_float(u1 << 16);
        float p = h0 * W_lin[tid] + h1 * W_lin[tid + 64];
#pragma unroll
        for (int off = 32; off; off >>= 1) p += __shfl_down(p, off);
        if (tid == 0) out[b] = p + b_lin[0];
    }
}

extern "C" void kernel_launch(void* const* d_in, const int* in_sizes, int n_in,
                              void* d_out, int out_size, void* d_ws, size_t ws_size,
                              hipStream_t stream) {
    const float* token = (const float*)d_in[0];
    const float* W_ih  = (const float*)d_in[1];
    const float* W_hh  = (const float*)d_in[2];
    const float* b_ih  = (const float*)d_in[3];
    const float* b_hh  = (const float*)d_in[4];
    const float* W_lin = (const float*)d_in[5];
    const float* b_lin = (const float*)d_in[6];
    float* out = (float*)d_out;

    hipLaunchKernelGGL(rnn_kernel, dim3(B_), dim3(256), 0, stream,
                       token, W_ih, W_hh, b_ih, b_hh, W_lin, b_lin, out);
}

// Round 16
// 197.815 us; speedup vs baseline: 1.2205x; 1.1398x over previous
//
#include <hip/hip_runtime.h>

#define B_ 512
#define T_ 512
#define I_ 64
#define H_ 128

// LDS: h ping/pong + dummy dump slots only
#define HB0    0
#define HB1    512
#define DUMMY  1024
#define LDS_SZ 1280

#define FM(a, x, w) "v_fmac_f32 v" #a ", v" #x ", v" #w "\n\t"
#define SC(n) "v_mul_f32 v" #n ", 0x4038aa3b, v" #n "\n\t"   // *= 2*log2(e)

#define CLOBS \
    "v48","v49","v50","v51","v52","v53","v54","v55","v56","v57","v58","v59", \
    "v60","v61","v62","v63","v64","v65","v66","v67","v68","v69","v70","v71", \
    "v72","v73","v74","v75","v76","v77","v78","v79","v80","v81","v82","v83", \
    "v84","v85","v86","v87","v88","v89","v90","v91","v92","v93","v94","v95", \
    "v96","v97","v98","v99","v100","v101","v102","v103","v104","v105","v106", \
    "v107","v108","v109","v110","v111","v112","v113","v114","v115","v116", \
    "v117","v118","v119","v120","v121","v122","v123","v124","v125","v126", \
    "v127","memory"

// Register map:
//   weights: wh j0..j3 = v80-87/88-95/96-103/104-111, wi j0..j3 = v112-115/
//            116-119/120-123/124-127                       (persistent)
//   tok sets: T0 v56-59, T1 v60-63, T2 v64-67, T3 v68-71   (4-deep prefetch)
//   h: v72-79; accums v48-51; temps v52-55
// Step t: tok(t) guaranteed by vmcnt(3); proj from regs fills h ds_read
// latency; reissue tok(t+4) into the freed set. DPP hazard s_nops proven.
#define RNN_STEP(TA, TB, TC, TD, HRD, HWR)                                    \
    asm volatile(                                                             \
        "ds_read_b128 v[72:75], %1\n\t"                                       \
        "ds_read_b128 v[76:79], %1 offset:256\n\t"                            \
        "s_waitcnt vmcnt(3)\n\t"                                              \
        "v_fma_f32 v48, v" #TA ", v112, %3\n\t"                               \
        "v_fma_f32 v49, v" #TA ", v116, %4\n\t"                               \
        "v_fma_f32 v50, v" #TA ", v120, %5\n\t"                               \
        "v_fma_f32 v51, v" #TA ", v124, %6\n\t"                               \
        FM(48,TB,113) FM(49,TB,117) FM(50,TB,121) FM(51,TB,125)               \
        FM(48,TC,114) FM(49,TC,118) FM(50,TC,122) FM(51,TC,126)               \
        FM(48,TD,115) FM(49,TD,119) FM(50,TD,123) FM(51,TD,127)               \
        "global_load_dwordx4 v[" #TA ":" #TD "], %0, %9\n\t"                  \
        "v_add_u32 %0, 0x100, %0\n\t"                                         \
        "v_and_b32 %0, 0x1ffff, %0\n\t"                                       \
        "s_waitcnt lgkmcnt(1)\n\t"                                            \
        FM(48,72,80) FM(49,72,88) FM(50,72,96)  FM(51,72,104)                 \
        FM(48,73,81) FM(49,73,89) FM(50,73,97)  FM(51,73,105)                 \
        FM(48,74,82) FM(49,74,90) FM(50,74,98)  FM(51,74,106)                 \
        FM(48,75,83) FM(49,75,91) FM(50,75,99)  FM(51,75,107)                 \
        "s_waitcnt lgkmcnt(0)\n\t"                                            \
        FM(48,76,84) FM(49,76,92) FM(50,76,100) FM(51,76,108)                 \
        FM(48,77,85) FM(49,77,93) FM(50,77,101) FM(51,77,109)                 \
        FM(48,78,86) FM(49,78,94) FM(50,78,102) FM(51,78,110)                 \
        FM(48,79,87) FM(49,79,95) FM(50,79,103) FM(51,79,111)                 \
        "s_nop 1\n\t"                                                         \
        "v_add_f32 v48, v48, v48 quad_perm:[1,0,3,2] row_mask:0xf bank_mask:0xf\n\t" \
        "v_add_f32 v49, v49, v49 quad_perm:[1,0,3,2] row_mask:0xf bank_mask:0xf\n\t" \
        "v_add_f32 v50, v50, v50 quad_perm:[1,0,3,2] row_mask:0xf bank_mask:0xf\n\t" \
        "v_add_f32 v51, v51, v51 quad_perm:[1,0,3,2] row_mask:0xf bank_mask:0xf\n\t" \
        "v_cndmask_b32 v52, v48, v49, %7\n\t"                                 \
        "v_cndmask_b32 v53, v50, v51, %7\n\t"                                 \
        "s_nop 0\n\t"                                                         \
        "v_add_f32 v52, v52, v52 quad_perm:[2,3,0,1] row_mask:0xf bank_mask:0xf\n\t" \
        "v_add_f32 v53, v53, v53 quad_perm:[2,3,0,1] row_mask:0xf bank_mask:0xf\n\t" \
        "v_cndmask_b32 v54, v52, v53, %8\n\t"                                 \
        "s_nop 1\n\t"                                                         \
        "v_add_f32 v54, v54, v54 row_shl:8 row_mask:0xf bank_mask:0x3\n\t"    \
        "s_nop 1\n\t"                                                         \
        "v_add_f32 v54, v54, v54 row_shl:4 row_mask:0xf bank_mask:0x1\n\t"    \
        "s_nop 1\n\t"                                                         \
        "v_exp_f32 v54, v54\n\t"                                              \
        "s_nop 0\n\t"                                                         \
        "v_add_f32 v54, 1.0, v54\n\t"                                         \
        "v_rcp_f32 v55, v54\n\t"                                              \
        "s_nop 0\n\t"                                                         \
        "v_fma_f32 v54, v55, -2.0, 1.0\n\t"                                   \
        "ds_write_b32 %2, v54\n\t"                                            \
        "s_waitcnt lgkmcnt(0)\n\t"                                            \
        "s_barrier"                                                           \
        : "+v"(voff)                                                          \
        : "v"(HRD), "v"(HWR), "v"(biasA), "v"(biasB), "v"(biasC),             \
          "v"(biasD), "s"(M1), "s"(M2), "s"(sbase)                            \
        : CLOBS)

__global__ __launch_bounds__(512) __attribute__((amdgpu_waves_per_eu(4, 4)))
void rnn_kernel(const float* __restrict__ token,
                const float* __restrict__ W_ih,
                const float* __restrict__ W_hh,
                const float* __restrict__ b_ih,
                const float* __restrict__ b_hh,
                const float* __restrict__ W_lin,
                const float* __restrict__ b_lin,
                float* __restrict__ out)
{
    __shared__ __align__(16) char lds[LDS_SZ];
    const unsigned lb =
        (unsigned)(uintptr_t)(__attribute__((address_space(3))) char*)lds;

    const int tid = threadIdx.x;
    const int e   = tid & 15;         // K-sixteenth
    const int G   = tid >> 4;         // output-quad id 0..31
    const int b   = blockIdx.x;
    const int jb  = 4 * G;

    // ---- weights into fixed v80-v127 ----
    {
        const float* pWh = W_hh + jb * H_ + e * 8;
        const float* pWi = W_ih + jb * I_ + e * 4;
        asm volatile(
            "global_load_dwordx4 v[80:83],   %0, off\n\t"
            "global_load_dwordx4 v[84:87],   %0, off offset:16\n\t"
            "global_load_dwordx4 v[88:91],   %0, off offset:512\n\t"
            "global_load_dwordx4 v[92:95],   %0, off offset:528\n\t"
            "global_load_dwordx4 v[96:99],   %0, off offset:1024\n\t"
            "global_load_dwordx4 v[100:103], %0, off offset:1040\n\t"
            "global_load_dwordx4 v[104:107], %0, off offset:1536\n\t"
            "global_load_dwordx4 v[108:111], %0, off offset:1552\n\t"
            "global_load_dwordx4 v[112:115], %1, off\n\t"
            "global_load_dwordx4 v[116:119], %1, off offset:256\n\t"
            "global_load_dwordx4 v[120:123], %1, off offset:512\n\t"
            "global_load_dwordx4 v[124:127], %1, off offset:768\n\t"
            "s_waitcnt vmcnt(0)\n\t"
            SC(80) SC(81) SC(82) SC(83) SC(84) SC(85) SC(86) SC(87)
            SC(88) SC(89) SC(90) SC(91) SC(92) SC(93) SC(94) SC(95)
            SC(96) SC(97) SC(98) SC(99) SC(100) SC(101) SC(102) SC(103)
            SC(104) SC(105) SC(106) SC(107) SC(108) SC(109) SC(110) SC(111)
            SC(112) SC(113) SC(114) SC(115) SC(116) SC(117) SC(118) SC(119)
            SC(120) SC(121) SC(122) SC(123) SC(124) SC(125) SC(126) SC(127)
            :: "v"(pWh), "v"(pWi) : CLOBS);
    }

    // biases pre-scaled by K2/16 (16 lanes each contribute the seed; /16 exact)
    const float k16 = 2.885390081777927f / 16.0f;
    const float biasA = (b_ih[jb + 0] + b_hh[jb + 0]) * k16;
    const float biasB = (b_ih[jb + 1] + b_hh[jb + 1]) * k16;
    const float biasC = (b_ih[jb + 2] + b_hh[jb + 2]) * k16;
    const float biasD = (b_ih[jb + 3] + b_hh[jb + 3]) * k16;
    const unsigned long long M1 = 0xAAAAAAAAAAAAAAAAULL;  // lanes with e&1
    const unsigned long long M2 = 0xCCCCCCCCCCCCCCCCULL;  // lanes with e&2

    // h float j at byte ((j>>2)&1)*256 + (j>>3)*16 + (j&3)*4 (proven)
    const int  jsel   = jb + (e & 3);
    const int  wbyte  = ((((jsel >> 2) & 1) * 16 + (jsel >> 3)) * 16) + (jsel & 3) * 4;
    const bool writer = (e < 4);
    const unsigned dmy = lb + DUMMY + (tid & 63) * 4;
    const unsigned hw0 = writer ? (lb + HB1 + wbyte) : dmy;  // buf0 -> buf1
    const unsigned hw1 = writer ? (lb + HB0 + wbyte) : dmy;  // buf1 -> buf0
    const unsigned hr0 = lb + HB0 + e * 16;
    const unsigned hr1 = lb + HB1 + e * 16;

    const float* tok_row = token + (size_t)b * T_ * I_;
    const unsigned long long sbase = (unsigned long long)(uintptr_t)tok_row;

    // ---- prologue: issue tok(0..3) into T0..T3; zero h buf0 ----
    {
        const unsigned v0 = e * 16;
        asm volatile(
            "global_load_dwordx4 v[56:59], %0, %1\n\t"
            "global_load_dwordx4 v[60:63], %0, %1 offset:256\n\t"
            "global_load_dwordx4 v[64:67], %0, %1 offset:512\n\t"
            "global_load_dwordx4 v[68:71], %0, %1 offset:768\n\t"
            :: "v"(v0), "s"(sbase) : CLOBS);
    }
    unsigned voff = e * 16 + 1024;    // next issue target: tok(4)
    if (tid < H_) *(float*)(lds + HB0 + tid * 4) = 0.0f;
    asm volatile("s_waitcnt lgkmcnt(0)\n\ts_barrier" ::: "memory");

#pragma unroll 1
    for (int t = 0; t < T_; t += 4) {
        RNN_STEP(56, 57, 58, 59, hr0, hw0);   // t+0: buf0 -> buf1
        RNN_STEP(60, 61, 62, 63, hr1, hw1);   // t+1: buf1 -> buf0
        RNN_STEP(64, 65, 66, 67, hr0, hw0);   // t+2
        RNN_STEP(68, 69, 70, 71, hr1, hw1);   // t+3
    }

    // drain the 4 dangling prefetches (wrapped in-row, harmless)
    asm volatile("s_waitcnt vmcnt(0)" ::: "memory");

    // ---- linear head on h buf0 (512 even steps -> final h in buf0) ----
    if (tid < 64) {
        const int a0 = tid, a1 = tid + 64;
        const int l0 = (((a0 >> 2) & 1) * 16 + (a0 >> 3)) * 4 + (a0 & 3);
        const int l1 = (((a1 >> 2) & 1) * 16 + (a1 >> 3)) * 4 + (a1 & 3);
        float p = *(const float*)(lds + HB0 + l0 * 4) * W_lin[a0]
                + *(const float*)(lds + HB0 + l1 * 4) * W_lin[a1];
#pragma unroll
        for (int off = 32; off; off >>= 1) p += __shfl_down(p, off);
        if (tid == 0) out[b] = p + b_lin[0];
    }
}

extern "C" void kernel_launch(void* const* d_in, const int* in_sizes, int n_in,
                              void* d_out, int out_size, void* d_ws, size_t ws_size,
                              hipStream_t stream) {
    const float* token = (const float*)d_in[0];
    const float* W_ih  = (const float*)d_in[1];
    const float* W_hh  = (const float*)d_in[2];
    const float* b_ih  = (const float*)d_in[3];
    const float* b_hh  = (const float*)d_in[4];
    const float* W_lin = (const float*)d_in[5];
    const float* b_lin = (const float*)d_in[6];
    float* out = (float*)d_out;

    hipLaunchKernelGGL(rnn_kernel, dim3(B_), dim3(512), 0, stream,
                       token, W_ih, W_hh, b_ih, b_hh, W_lin, b_lin, out);
}